// Round 18
// baseline (2401.169 us; speedup 1.0000x reference)
//
#include <hip/hip_runtime.h>
#include <cstdint>
#include <cstddef>

#define TSTEPS 100
#define NB 256
#define INF 2312
#define HIDN 512
#define NOUT 10

// ws layout (float offsets)
#define OFF_WT  0                 // 262144 floats (w_rec transposed, 1 MB)
#define OFF_ZB  262144            // 65536 floats = [2][256][512] u8 z-transit
#define OFF_CTR 327680            // 1024 u32: 32 group counters (stride 32); [1023]=mode
#define OFF_FLG 328704            // 2048 u32: 800 ci-tile flags
#define OFF_CI  330752            // 13107200 floats (input-projection cache)
#define WS_FLOATS 13437952        // 53.75 MB

typedef double f64x4 __attribute__((ext_vector_type(4)));

// D-layout candidates for mfma_f64_16x16x4: lane l, reg r -> (row m, col n)
__device__ __forceinline__ void dpos_f64(int di, int lane, int r, int& m, int& n) {
    const int l16 = lane & 15, kq = lane >> 4;
    switch (di) {
    case 0:  m = 4 * kq + r;         n = l16;                break;
    case 1:  m = l16;                n = 4 * kq + r;         break;
    case 2:  m = kq + 4 * r;         n = l16;                break;
    case 3:  m = l16;                n = kq + 4 * r;         break;
    case 4:  m = lane >> 2;          n = 4 * (lane & 3) + r; break;
    default: n = lane >> 2;          m = 4 * (lane & 3) + r; break;
    }
}

// build w_recT[j][h] = w_rec[h][j]; zero z-transit + counters + mode + flags
__global__ __launch_bounds__(256) void init_kernel(float* __restrict__ ws,
                                                   const float* __restrict__ w_rec) {
    int n = blockIdx.x * 256 + threadIdx.x;
    if (n < HIDN * HIDN) {
        int j = n >> 9, h = n & 511;
        ws[n] = w_rec[h * HIDN + j];
    } else if (n < OFF_CI) {
        ws[n] = 0.0f;
    }
}

// Exact-integer layout decoder (VERBATIM R14; HW-verified R14/R16/R17).
__global__ __launch_bounds__(64) void probe_kernel(unsigned int* __restrict__ mode_out) {
    const int l = threadIdx.x;
    __shared__ unsigned int maskls;
    if (l == 0) maskls = 0xFFFFFFu;
    __syncthreads();
    double a1v = 1.0 + 3.0 * (double)l, b1v = 2.0 + 5.0 * (double)l;
    double a2v = 7.0 - 2.0 * (double)l, b2v = -3.0 + (double)l;
    f64x4 pacc;
#pragma unroll
    for (int r = 0; r < 4; ++r) pacc[r] = 1000.0 * r + 17.0 * l;
    pacc = __builtin_amdgcn_mfma_f64_16x16x4f64(a1v, b1v, pacc, 0, 0, 0);
    pacc = __builtin_amdgcn_mfma_f64_16x16x4f64(a2v, b2v, pacc, 0, 0, 0);
    unsigned int my = 0;
    for (int ai = 0; ai < 2; ++ai)
        for (int bi = 0; bi < 2; ++bi)
            for (int di = 0; di < 6; ++di) {
                bool ok = true;
                for (int r = 0; r < 4; ++r) {
                    int m, n; dpos_f64(di, l, r, m, n);
                    double e = 1000.0 * r + 17.0 * l;
                    for (int k = 0; k < 4; ++k) {
                        int lA = ai ? (4 * m + k) : (m + 16 * k);
                        int lB = bi ? (4 * n + k) : (n + 16 * k);
                        e += (1.0 + 3.0 * (double)lA) * (2.0 + 5.0 * (double)lB)
                           + (7.0 - 2.0 * (double)lA) * (-3.0 + (double)lB);
                    }
                    ok = ok && (pacc[r] == e);
                }
                if (ok) my |= 1u << (ai * 12 + bi * 6 + di);
            }
    atomicAnd(&maskls, my);
    __syncthreads();
    if (l == 0) mode_out[0] = maskls ? (unsigned)(__ffs((int)maskls) - 1) : 255u;
}

// MEGA v3: block-role overlap with an R16-efficiency producer.
//  blocks 0..255  : fused stepper (VERBATIM arithmetic) + per-tile flag poll.
//  blocks 256..1055: gemm producer, ONE 128x128 ci tile each, 8 waves, wave =
//     16 rows x 128 cols (acc[8]) -> per-wave feed ratio IDENTICAL to R16's
//     70%-MfmaUtil kernel; R16 staging split; stride-136 LDS (reads <=2-way).
//     Tiles by-ascending == timestep order. MFMA per-element k-sequence
//     IDENTICAL to R14/R16 -> bit-identical ci.
// Deadlock-free: 34.8KB LDS + launch_bounds(512,4) -> 2 blocks/CU; 256 fused
// blocks fit 1/CU avg; gemm blocks never wait -> progress any dispatch order.
__global__ __launch_bounds__(512, 4) void mega2(
        const float* __restrict__ X, const float* __restrict__ Win,
        const float* __restrict__ wT, const float* __restrict__ w_out,
        float* __restrict__ ci, float* __restrict__ out,
        unsigned char* __restrict__ zb, unsigned int* __restrict__ ctr,
        unsigned int* __restrict__ flg, const unsigned int* __restrict__ modep) {
    __shared__ __align__(16) unsigned char smem[34816];   // 2 x 32 x 136 floats
    const int i = (int)blockIdx.x;
    const int tid = threadIdx.x;

    if (i >= 256) {
        // ========================= GEMM PRODUCER =========================
        const int j = i - 256;                 // 0..799, by-major (time order)
        const int by = j >> 2, bx = j & 3;
        const int row0 = by * 128, col0 = bx * 128;
        float (*As)[136] = (float(*)[136])smem;             // 17408 B
        float (*Bs)[136] = (float(*)[136])(smem + 17408);   // 17408 B
        const unsigned int mode = modep[0];
        const int lane = tid & 63, wv = tid >> 6;
        const int sr = tid >> 2, sk = (tid & 3) * 8;   // staging: row/col, k-base

        float4 va[2], vb[2];
#pragma unroll
        for (int q = 0; q < 2; ++q) {
            int gk = sk + q * 4;
            va[q] = *(const float4*)(X + (size_t)(row0 + sr) * INF + gk);
            vb[q] = *(const float4*)(Win + (size_t)(col0 + sr) * INF + gk);
        }

        if (mode < 24u) {
            const int di = (int)(mode % 6u), bi = (int)((mode / 6u) & 1u),
                      ai = (int)(mode / 12u);
            const int a_m = ai ? (lane >> 2) : (lane & 15);
            const int a_k = ai ? (lane & 3) : (lane >> 4);
            const int b_n = bi ? (lane >> 2) : (lane & 15);
            const int b_k = bi ? (lane & 3) : (lane >> 4);
            f64x4 acc[8] = {};
            for (int k0 = 0; k0 < INF; k0 += 32) {
                __syncthreads();
#pragma unroll
                for (int q = 0; q < 2; ++q) {
                    int kc = sk + q * 4;
                    As[kc + 0][sr] = va[q].x; As[kc + 1][sr] = va[q].y;
                    As[kc + 2][sr] = va[q].z; As[kc + 3][sr] = va[q].w;
                    Bs[kc + 0][sr] = vb[q].x; Bs[kc + 1][sr] = vb[q].y;
                    Bs[kc + 2][sr] = vb[q].z; Bs[kc + 3][sr] = vb[q].w;
                }
                __syncthreads();
                const int kn = k0 + 32;
                if (kn < INF) {
#pragma unroll
                    for (int q = 0; q < 2; ++q) {
                        int gk = kn + sk + q * 4;
                        float4 a = make_float4(0.f, 0.f, 0.f, 0.f);
                        float4 b = make_float4(0.f, 0.f, 0.f, 0.f);
                        if (gk < INF) {   // INF%4==0 -> full float4 in-bounds
                            a = *(const float4*)(X + (size_t)(row0 + sr) * INF + gk);
                            b = *(const float4*)(Win + (size_t)(col0 + sr) * INF + gk);
                        }
                        va[q] = a; vb[q] = b;
                    }
                }
#pragma unroll
                for (int s = 0; s < 8; ++s) {
                    double a = (double)As[s * 4 + a_k][wv * 16 + a_m];
#pragma unroll
                    for (int nt = 0; nt < 8; ++nt) {
                        double b = (double)Bs[s * 4 + b_k][nt * 16 + b_n];
                        acc[nt] = __builtin_amdgcn_mfma_f64_16x16x4f64(a, b, acc[nt], 0, 0, 0);
                    }
                }
            }
#pragma unroll
            for (int nt = 0; nt < 8; ++nt)
#pragma unroll
                for (int r = 0; r < 4; ++r) {
                    int m, n; dpos_f64(di, lane, r, m, n);
                    ci[(size_t)(row0 + wv * 16 + m) * HIDN + col0 + nt * 16 + n]
                        = (float)acc[nt][r];
                }
        } else {
            // vector fallback: FROZEN per-element ascending-k chain, 2 passes
            const int r2 = tid >> 2, cb0 = (tid & 3) * 32;
            for (int p = 0; p < 2; ++p) {
                double accv[16] = {};
                float4 wa[2], wb[2];
#pragma unroll
                for (int q = 0; q < 2; ++q) {
                    int gk = sk + q * 4;
                    wa[q] = *(const float4*)(X + (size_t)(row0 + sr) * INF + gk);
                    wb[q] = *(const float4*)(Win + (size_t)(col0 + sr) * INF + gk);
                }
                for (int k0 = 0; k0 < INF; k0 += 32) {
                    __syncthreads();
#pragma unroll
                    for (int q = 0; q < 2; ++q) {
                        int kc = sk + q * 4;
                        As[kc + 0][sr] = wa[q].x; As[kc + 1][sr] = wa[q].y;
                        As[kc + 2][sr] = wa[q].z; As[kc + 3][sr] = wa[q].w;
                        Bs[kc + 0][sr] = wb[q].x; Bs[kc + 1][sr] = wb[q].y;
                        Bs[kc + 2][sr] = wb[q].z; Bs[kc + 3][sr] = wb[q].w;
                    }
                    __syncthreads();
                    const int kn = k0 + 32;
                    if (kn < INF) {
#pragma unroll
                        for (int q = 0; q < 2; ++q) {
                            int gk = kn + sk + q * 4;
                            float4 a = make_float4(0.f, 0.f, 0.f, 0.f);
                            float4 b = make_float4(0.f, 0.f, 0.f, 0.f);
                            if (gk < INF) {
                                a = *(const float4*)(X + (size_t)(row0 + sr) * INF + gk);
                                b = *(const float4*)(Win + (size_t)(col0 + sr) * INF + gk);
                            }
                            wa[q] = a; wb[q] = b;
                        }
                    }
#pragma unroll 4
                    for (int kk = 0; kk < 32; ++kk) {
                        double ad = (double)As[kk][r2];
#pragma unroll
                        for (int jj = 0; jj < 16; ++jj)
                            accv[jj] += ad * (double)Bs[kk][cb0 + p * 16 + jj];
                    }
                }
#pragma unroll
                for (int jj = 0; jj < 16; ++jj)
                    ci[(size_t)(row0 + r2) * HIDN + col0 + cb0 + p * 16 + jj]
                        = (float)accv[jj];
            }
        }
        // publish tile flag (stores drained by syncthreads; fence for cross-XCD)
        __syncthreads();
        if (tid == 0) {
            __threadfence();
            __hip_atomic_store(&flg[j], 1u, __ATOMIC_RELEASE,
                               __HIP_MEMORY_SCOPE_AGENT);
        }
        return;
    }

    // ========================= FUSED STEPPER (verbatim) =========================
    float* zfb = (float*)smem;                             // 16 KB
    float (*wout2)[512] = (float(*)[512])(smem + 16384);   // 4 KB
    const int wv = tid >> 6, lane = tid & 63;
    const int c = (i >> 3) & 7;                    // h-chunk / group member
    const int g = (i & 7) | ((i >> 6) << 3);       // group 0..31
    const int b0 = g * 8;

    float wreg[64];
#pragma unroll
    for (int qq = 0; qq < 64; ++qq)
        wreg[qq] = wT[(size_t)((wv << 6) + qq) * HIDN + (c << 6) + lane];

    if (tid < 512) {
        wout2[0][tid] = w_out[c * HIDN + tid];
        wout2[1][tid] = (c < 2) ? w_out[(8 + c) * HIDN + tid] : 0.0f;
    }
    for (int idx = tid; idx < 4096; idx += 512) zfb[idx] = 0.0f;  // z_{-1}=0
    __syncthreads();

    unsigned char* zbA = zb + (size_t)b0 * HIDN;            // [b][j] u8
    unsigned char* zbB = zb + 131072 + (size_t)b0 * HIDN;
    unsigned int* myctr = ctr + g * 32;                     // 128B apart

    float pos = 0.0f;                  // fold phase: thread = (batch wv, h lane)
    float vA = 0.f, iA = 0.f, vB = 0.f, iB = 0.f;   // LI state on lane 0

    for (int t = 0; t < TSTEPS; ++t) {
        // ---- wait for this step's ci tile (proven tid0-acquire pattern) ----
        {
            const int fidx = (2 * t + (g >> 4)) * 4 + (c >> 1);
            if (tid == 0) {
                while (__hip_atomic_load(&flg[fidx], __ATOMIC_ACQUIRE,
                                         __HIP_MEMORY_SCOPE_AGENT) == 0u)
                    __builtin_amdgcn_s_sleep(8);
            }
            __syncthreads();
        }

        // ---- gather (frozen fmac chains, verbatim R9) ----
        float f[8] = {0.f, 0.f, 0.f, 0.f, 0.f, 0.f, 0.f, 0.f};
#pragma unroll
        for (int q4 = 0; q4 < 16; ++q4) {
            float4 z4[8];
#pragma unroll
            for (int b = 0; b < 8; ++b)
                z4[b] = *(const float4*)&zfb[b * 512 + (wv << 6) + q4 * 4];
#pragma unroll
            for (int b = 0; b < 8; ++b) {
                f[b] = __fmaf_rn(z4[b].x, wreg[q4 * 4 + 0], f[b]);
                f[b] = __fmaf_rn(z4[b].y, wreg[q4 * 4 + 1], f[b]);
                f[b] = __fmaf_rn(z4[b].z, wreg[q4 * 4 + 2], f[b]);
                f[b] = __fmaf_rn(z4[b].w, wreg[q4 * 4 + 3], f[b]);
            }
        }
        __syncthreads();   // B1: all zf reads done; region becomes fbufT
#pragma unroll
        for (int b = 0; b < 8; ++b)
            zfb[((wv << 3) + b) * 64 + lane] = f[b];   // fbufT[c2=wv][b][h]
        __syncthreads();   // B2: partials published

        double acc = 0.0;
#pragma unroll
        for (int c2 = 0; c2 < 8; ++c2)
            acc += (double)zfb[((c2 << 3) + wv) * 64 + lane];
        float rec32 = (float)acc;
        float civ = ci[((size_t)t * NB + (b0 + wv)) * HIDN + (c << 6) + lane];
        float cur = __fadd_rn(__fadd_rn(civ, rec32), 1e-4f);   // (in+rec)+I_APP
        float mc = __fmul_rn(2.5e5f, cur);                     // MU*cur
        pos = __fadd_rn(pos, __fmul_rn(1e-10f, mc));           // pos += DT*(..)
        bool zbit = __fsub_rn(pos, 2.5e-8f) > 0.0f;            // pos-W2 > 0
        pos = zbit ? 0.0f : pos;
        unsigned char* zw = (t & 1) ? zbB : zbA;
        zw[wv * HIDN + (c << 6) + lane] = zbit ? 1 : 0;        // publish u8

        __syncthreads();
        if (tid == 0) {
            __hip_atomic_fetch_add(myctr, 1u, __ATOMIC_ACQ_REL,
                                   __HIP_MEMORY_SCOPE_AGENT);
            const unsigned int tgt = 8u * (unsigned)(t + 1);
            while (__hip_atomic_load(myctr, __ATOMIC_ACQUIRE,
                                     __HIP_MEMORY_SCOPE_AGENT) < tgt)
                __builtin_amdgcn_s_sleep(2);
        }
        __syncthreads();   // B3: group's z_t visible (acquire fence on ctr)

        {
            const int bb = tid >> 6, j8 = (tid & 63) * 8;
            uint2 ld = *(const uint2*)(zw + bb * HIDN + j8);
            float4 o0, o1;
            o0.x = (float)(ld.x & 255u);         o0.y = (float)((ld.x >> 8) & 255u);
            o0.z = (float)((ld.x >> 16) & 255u); o0.w = (float)(ld.x >> 24);
            o1.x = (float)(ld.y & 255u);         o1.y = (float)((ld.y >> 8) & 255u);
            o1.z = (float)((ld.y >> 16) & 255u); o1.w = (float)(ld.y >> 24);
            *(float4*)&zfb[bb * 512 + j8] = o0;
            *(float4*)&zfb[bb * 512 + j8 + 4] = o1;
        }
        __syncthreads();   // B4: zf ready for LI + next gather

#pragma unroll
        for (int oo = 0; oo < 2; ++oo) {
            int o = (oo == 0) ? c : (c < 2 ? 8 + c : -1);
            if (o < 0) continue;
            double part = 0.0;
#pragma unroll
            for (int c2 = 0; c2 < 8; ++c2) {
                double zfv = (double)zfb[wv * 512 + (c2 << 6) + lane];
                part = __fma_rn(zfv, (double)wout2[oo][(c2 << 6) + lane], part);
            }
#pragma unroll
            for (int off = 32; off > 0; off >>= 1) part += __shfl_down(part, off);
            if (lane == 0) {
                float inp = (float)part;
                float vvv = (oo == 0) ? vA : vB;
                float iiv = (oo == 0) ? iA : iB;
                float vn = __fadd_rn(vvv, __fmul_rn(1e-8f, __fsub_rn(iiv, vvv)));
                float t2 = __fmul_rn(2e-8f, iiv);
                float in2 = __fadd_rn(__fsub_rn(iiv, t2), inp);
                if (oo == 0) { vA = vn; iA = in2; } else { vB = vn; iB = in2; }
                out[((size_t)t * NB + (b0 + wv)) * NOUT + o] = vn;
            }
        }
    }
}

extern "C" void kernel_launch(void* const* d_in, const int* in_sizes, int n_in,
                              void* d_out, int out_size, void* d_ws, size_t ws_size,
                              hipStream_t stream) {
    (void)in_sizes; (void)n_in; (void)out_size;
    const float* x     = (const float*)d_in[0];
    const float* w_in  = (const float*)d_in[1];
    const float* w_rec = (const float*)d_in[2];
    const float* w_out = (const float*)d_in[3];
    float* out = (float*)d_out;
    float* ws  = (float*)d_ws;
    if (ws_size < (size_t)WS_FLOATS * 4) return;

    float* wT = ws + OFF_WT;
    unsigned char* zb = (unsigned char*)(ws + OFF_ZB);
    unsigned int* ctr = (unsigned int*)(ws + OFF_CTR);
    unsigned int* mode = ctr + 1023;   // unused counter slot (g*32 <= 992)
    unsigned int* flg = (unsigned int*)(ws + OFF_FLG);
    float* ci = ws + OFF_CI;

    hipLaunchKernelGGL(init_kernel, dim3((OFF_CI + 255) / 256), dim3(256), 0,
                       stream, ws, w_rec);
    hipLaunchKernelGGL(probe_kernel, dim3(1), dim3(64), 0, stream, mode);
    hipLaunchKernelGGL(mega2, dim3(256 + 800), dim3(512), 0, stream,
                       x, w_in, wT, w_out, ci, out, zb, ctr, flg, mode);
}

// Round 19
// 1575.785 us; speedup vs baseline: 1.5238x; 1.5238x over previous
//
#include <hip/hip_runtime.h>
#include <cstdint>
#include <cstddef>

#define TSTEPS 100
#define NB 256
#define INF 2312
#define HIDN 512
#define NOUT 10

// ws layout (float offsets) — as R16; ctr[1023] = MFMA mode slot
#define OFF_WT  0                 // 262144 floats (w_rec transposed, 1 MB)
#define OFF_ZB  262144            // 65536 floats = [2][256][512] u8 z-transit
#define OFF_CTR 327680            // 1024 u32; [1023]=mode
#define OFF_CI  328704            // 13107200 floats (input-projection cache)
#define WS_FLOATS 13435904        // 53.7 MB

typedef double f64x4 __attribute__((ext_vector_type(4)));

// D-layout candidates for mfma_f64_16x16x4: lane l, reg r -> (row m, col n)
__device__ __forceinline__ void dpos_f64(int di, int lane, int r, int& m, int& n) {
    const int l16 = lane & 15, kq = lane >> 4;
    switch (di) {
    case 0:  m = 4 * kq + r;         n = l16;                break;
    case 1:  m = l16;                n = 4 * kq + r;         break;
    case 2:  m = kq + 4 * r;         n = l16;                break;
    case 3:  m = l16;                n = kq + 4 * r;         break;
    case 4:  m = lane >> 2;          n = 4 * (lane & 3) + r; break;
    default: n = lane >> 2;          m = 4 * (lane & 3) + r; break;
    }
}

// build w_recT[j][h] = w_rec[h][j]; zero z-transit + counters + mode slot
__global__ __launch_bounds__(256) void init_kernel(float* __restrict__ ws,
                                                   const float* __restrict__ w_rec) {
    int n = blockIdx.x * 256 + threadIdx.x;
    if (n < HIDN * HIDN) {
        int j = n >> 9, h = n & 511;
        ws[n] = w_rec[h * HIDN + j];
    } else if (n < OFF_CI) {
        ws[n] = 0.0f;
    }
}

// Exact-integer layout decoder (VERBATIM R14; HW-verified R14/R16).
__global__ __launch_bounds__(64) void probe_kernel(unsigned int* __restrict__ mode_out) {
    const int l = threadIdx.x;
    __shared__ unsigned int maskls;
    if (l == 0) maskls = 0xFFFFFFu;
    __syncthreads();
    double a1v = 1.0 + 3.0 * (double)l, b1v = 2.0 + 5.0 * (double)l;
    double a2v = 7.0 - 2.0 * (double)l, b2v = -3.0 + (double)l;
    f64x4 pacc;
#pragma unroll
    for (int r = 0; r < 4; ++r) pacc[r] = 1000.0 * r + 17.0 * l;
    pacc = __builtin_amdgcn_mfma_f64_16x16x4f64(a1v, b1v, pacc, 0, 0, 0);
    pacc = __builtin_amdgcn_mfma_f64_16x16x4f64(a2v, b2v, pacc, 0, 0, 0);
    unsigned int my = 0;
    for (int ai = 0; ai < 2; ++ai)
        for (int bi = 0; bi < 2; ++bi)
            for (int di = 0; di < 6; ++di) {
                bool ok = true;
                for (int r = 0; r < 4; ++r) {
                    int m, n; dpos_f64(di, l, r, m, n);
                    double e = 1000.0 * r + 17.0 * l;
                    for (int k = 0; k < 4; ++k) {
                        int lA = ai ? (4 * m + k) : (m + 16 * k);
                        int lB = bi ? (4 * n + k) : (n + 16 * k);
                        e += (1.0 + 3.0 * (double)lA) * (2.0 + 5.0 * (double)lB)
                           + (7.0 - 2.0 * (double)lA) * (-3.0 + (double)lB);
                    }
                    ok = ok && (pacc[r] == e);
                }
                if (ok) my |= 1u << (ai * 12 + bi * 6 + di);
            }
    atomicAnd(&maskls, my);
    __syncthreads();
    if (l == 0) mode_out[0] = maskls ? (unsigned)(__ffs((int)maskls) - 1) : 255u;
}

// MFMA f64 GEMM: VERBATIM R16 gemm_mfma3 (1211us, MfmaUtil 70%, ci fingerprint-
// verified). 64x128 tile, float LDS, launch_bounds(256,3).
__global__ __launch_bounds__(256, 3) void gemm_mfma3(const float* __restrict__ X,
        const float* __restrict__ Win, float* __restrict__ C,
        const unsigned int* __restrict__ modep) {
    const unsigned int mode = modep[0];
    if (mode >= 24u) return;
    const int di = (int)(mode % 6u), bi = (int)((mode / 6u) & 1u), ai = (int)(mode / 12u);
    __shared__ float As[32][72];
    __shared__ float Bs[32][144];
    const int tid = threadIdx.x;
    const int lane = tid & 63, wv = tid >> 6;
    const int a_m = ai ? (lane >> 2) : (lane & 15);
    const int a_k = ai ? (lane & 3) : (lane >> 4);
    const int b_n = bi ? (lane >> 2) : (lane & 15);
    const int b_k = bi ? (lane & 3) : (lane >> 4);
    const int row0 = blockIdx.y * 64, col0 = blockIdx.x * 128;
    const int sra = tid >> 2, ska = (tid & 3) * 8;
    const int srb = tid >> 1, skb = (tid & 1) * 16;

    float4 va[2], vb[4];
#pragma unroll
    for (int q = 0; q < 2; ++q)
        va[q] = *(const float4*)(X + (size_t)(row0 + sra) * INF + ska + q * 4);
#pragma unroll
    for (int q = 0; q < 4; ++q)
        vb[q] = *(const float4*)(Win + (size_t)(col0 + srb) * INF + skb + q * 4);

    f64x4 acc[8] = {};
    for (int k0 = 0; k0 < INF; k0 += 32) {
        __syncthreads();
#pragma unroll
        for (int q = 0; q < 2; ++q) {
            int kc = ska + q * 4;
            As[kc + 0][sra] = va[q].x; As[kc + 1][sra] = va[q].y;
            As[kc + 2][sra] = va[q].z; As[kc + 3][sra] = va[q].w;
        }
#pragma unroll
        for (int q = 0; q < 4; ++q) {
            int kc = skb + q * 4;
            Bs[kc + 0][srb] = vb[q].x; Bs[kc + 1][srb] = vb[q].y;
            Bs[kc + 2][srb] = vb[q].z; Bs[kc + 3][srb] = vb[q].w;
        }
        __syncthreads();
        const int kn = k0 + 32;
        if (kn < INF) {
#pragma unroll
            for (int q = 0; q < 2; ++q) {
                int gk = kn + ska + q * 4;
                float4 a = make_float4(0.f, 0.f, 0.f, 0.f);
                if (gk < INF)   // INF%4==0 -> full float4 in-bounds
                    a = *(const float4*)(X + (size_t)(row0 + sra) * INF + gk);
                va[q] = a;
            }
#pragma unroll
            for (int q = 0; q < 4; ++q) {
                int gk = kn + skb + q * 4;
                float4 b = make_float4(0.f, 0.f, 0.f, 0.f);
                if (gk < INF)
                    b = *(const float4*)(Win + (size_t)(col0 + srb) * INF + gk);
                vb[q] = b;
            }
        }
#pragma unroll
        for (int s = 0; s < 8; ++s) {
            double a = (double)As[s * 4 + a_k][wv * 16 + a_m];
#pragma unroll
            for (int nt = 0; nt < 8; ++nt) {
                double b = (double)Bs[s * 4 + b_k][nt * 16 + b_n];
                acc[nt] = __builtin_amdgcn_mfma_f64_16x16x4f64(a, b, acc[nt], 0, 0, 0);
            }
        }
    }
#pragma unroll
    for (int nt = 0; nt < 8; ++nt)
#pragma unroll
        for (int r = 0; r < 4; ++r) {
            int m, n; dpos_f64(di, lane, r, m, n);
            C[(size_t)(row0 + wv * 16 + m) * HIDN + col0 + nt * 16 + n]
                = (float)acc[nt][r];
        }
}

// Vector GEMM fallback: VERBATIM R10 (frozen chain). Runs only if mode==255.
__global__ __launch_bounds__(256, 2) void gemm_vec(const float* __restrict__ X,
        const float* __restrict__ Win, float* __restrict__ C,
        const unsigned int* __restrict__ modep) {
    if (modep[0] < 24u) return;
    __shared__ double As[32][130];
    __shared__ double Bs[32][144];
    const int tid = threadIdx.x;
    const int tx = tid & 15;
    const int ty = tid >> 4;
    const int row0 = blockIdx.y * 128, col0 = blockIdx.x * 128;
    const int sr = tid >> 1, sk = (tid & 1) * 16;
    const int srz = sr + (sr >> 3);
    float4 va[4], vb[4];
#pragma unroll
    for (int q = 0; q < 4; ++q) {
        int gk = sk + q * 4;
        va[q] = *(const float4*)(X + (size_t)(row0 + sr) * INF + gk);
        vb[q] = *(const float4*)(Win + (size_t)(col0 + sr) * INF + gk);
    }
    double acc[8][8] = {};
    for (int k0 = 0; k0 < INF; k0 += 32) {
        __syncthreads();
#pragma unroll
        for (int q = 0; q < 4; ++q) {
            int kc = sk + q * 4;
            As[kc + 0][sr] = (double)va[q].x; As[kc + 1][sr] = (double)va[q].y;
            As[kc + 2][sr] = (double)va[q].z; As[kc + 3][sr] = (double)va[q].w;
            Bs[kc + 0][srz] = (double)vb[q].x; Bs[kc + 1][srz] = (double)vb[q].y;
            Bs[kc + 2][srz] = (double)vb[q].z; Bs[kc + 3][srz] = (double)vb[q].w;
        }
        __syncthreads();
        const int kn = k0 + 32;
        if (kn < INF) {
#pragma unroll
            for (int q = 0; q < 4; ++q) {
                int gk = kn + sk + q * 4;
                float4 a = make_float4(0.f, 0.f, 0.f, 0.f);
                float4 b = make_float4(0.f, 0.f, 0.f, 0.f);
                if (gk < INF) {
                    a = *(const float4*)(X + (size_t)(row0 + sr) * INF + gk);
                    b = *(const float4*)(Win + (size_t)(col0 + sr) * INF + gk);
                }
                va[q] = a; vb[q] = b;
            }
        }
#pragma unroll 4
        for (int kk = 0; kk < 32; ++kk) {
            double ad[8], bd[8];
#pragma unroll
            for (int i = 0; i < 8; ++i) ad[i] = As[kk][ty * 8 + i];
#pragma unroll
            for (int j = 0; j < 8; ++j) bd[j] = Bs[kk][9 * tx + j];
#pragma unroll
            for (int i = 0; i < 8; ++i)
#pragma unroll
                for (int j = 0; j < 8; ++j)
                    acc[i][j] += ad[i] * bd[j];
        }
    }
#pragma unroll
    for (int i = 0; i < 8; ++i) {
#pragma unroll
        for (int jj = 0; jj < 2; ++jj) {
            float4 o;
            o.x = (float)acc[i][jj * 4 + 0]; o.y = (float)acc[i][jj * 4 + 1];
            o.z = (float)acc[i][jj * 4 + 2]; o.w = (float)acc[i][jj * 4 + 3];
            *(float4*)(C + (size_t)(row0 + ty * 8 + i) * HIDN + col0 + tx * 8 + jj * 4) = o;
        }
    }
}

// Fused stepper with TAG-EMBEDDED z exchange: the z byte itself carries the
// step tag (byte = ((t>>1)+1)<<1 | z), double-buffered by t&1. Consumers poll
// the data bytes directly until all tags match -> ONE L2 trip per step, no
// counter RMW, no fences (data == flag; per-byte single writer; 2-step buffer
// reuse is ordered by program order: P publishes t+1 only after pulling t,
// which implies every member already pulled t-1). zf floats entering the
// gather are identical {0,1} -> ALL fp arithmetic VERBATIM R9-R16.
__global__ __launch_bounds__(512) void fused_tag(const float* __restrict__ ci,
        const float* __restrict__ wT, const float* __restrict__ w_out,
        float* __restrict__ out, unsigned char* __restrict__ zb) {
    __shared__ float zfb[4096];        // 16 KB union: zf[b][j] | fbufT[c2][b][h]
    __shared__ float wout2[2][512];    // 4 KB
    const int tid = threadIdx.x;
    const int wv = tid >> 6, lane = tid & 63;
    const int i = (int)blockIdx.x;
    const int c = (i >> 3) & 7;                    // h-chunk / group member
    const int g = (i & 7) | ((i >> 6) << 3);       // group 0..31 (co-XCD)
    const int b0 = g * 8;

    float wreg[64];
#pragma unroll
    for (int qq = 0; qq < 64; ++qq)
        wreg[qq] = wT[(size_t)((wv << 6) + qq) * HIDN + (c << 6) + lane];

    if (tid < 512) {
        wout2[0][tid] = w_out[c * HIDN + tid];
        wout2[1][tid] = (c < 2) ? w_out[(8 + c) * HIDN + tid] : 0.0f;
    }
    for (int idx = tid; idx < 4096; idx += 512) zfb[idx] = 0.0f;  // z_{-1}=0
    __syncthreads();

    unsigned char* zbA = zb + (size_t)b0 * HIDN;            // [b][j] u8
    unsigned char* zbB = zb + 131072 + (size_t)b0 * HIDN;

    float pos = 0.0f;                  // fold phase: thread = (batch wv, h lane)
    float vA = 0.f, iA = 0.f, vB = 0.f, iB = 0.f;   // LI state on lane 0

    for (int t = 0; t < TSTEPS; ++t) {
        // ---- gather (frozen fmac chains, verbatim R9) ----
        float f[8] = {0.f, 0.f, 0.f, 0.f, 0.f, 0.f, 0.f, 0.f};
#pragma unroll
        for (int q4 = 0; q4 < 16; ++q4) {
            float4 z4[8];
#pragma unroll
            for (int b = 0; b < 8; ++b)
                z4[b] = *(const float4*)&zfb[b * 512 + (wv << 6) + q4 * 4];
#pragma unroll
            for (int b = 0; b < 8; ++b) {
                f[b] = __fmaf_rn(z4[b].x, wreg[q4 * 4 + 0], f[b]);
                f[b] = __fmaf_rn(z4[b].y, wreg[q4 * 4 + 1], f[b]);
                f[b] = __fmaf_rn(z4[b].z, wreg[q4 * 4 + 2], f[b]);
                f[b] = __fmaf_rn(z4[b].w, wreg[q4 * 4 + 3], f[b]);
            }
        }
        __syncthreads();   // B1: all zf reads done; region becomes fbufT
#pragma unroll
        for (int b = 0; b < 8; ++b)
            zfb[((wv << 3) + b) * 64 + lane] = f[b];   // fbufT[c2=wv][b][h]
        __syncthreads();   // B2: partials published

        // ---- fold + neuron update (frozen) + tagged z publish ----
        double acc = 0.0;
#pragma unroll
        for (int c2 = 0; c2 < 8; ++c2)
            acc += (double)zfb[((c2 << 3) + wv) * 64 + lane];
        float rec32 = (float)acc;
        float civ = ci[((size_t)t * NB + (b0 + wv)) * HIDN + (c << 6) + lane];
        float cur = __fadd_rn(__fadd_rn(civ, rec32), 1e-4f);   // (in+rec)+I_APP
        float mc = __fmul_rn(2.5e5f, cur);                     // MU*cur
        pos = __fadd_rn(pos, __fmul_rn(1e-10f, mc));           // pos += DT*(..)
        bool zbit = __fsub_rn(pos, 2.5e-8f) > 0.0f;            // pos-W2 > 0
        pos = zbit ? 0.0f : pos;
        unsigned char* zw = (t & 1) ? zbB : zbA;
        const unsigned int tag2 = ((unsigned)(t >> 1) + 1u) << 1;   // <=101
        __hip_atomic_store(&zw[wv * HIDN + (c << 6) + lane],
                           (unsigned char)(tag2 | (zbit ? 1u : 0u)),
                           __ATOMIC_RELAXED, __HIP_MEMORY_SCOPE_AGENT);
        __syncthreads();   // B3: fbufT reads done -> zfb reusable as zf

        // ---- pull z_t: poll tagged bytes (data == flag) ----
        {
            const int bb = tid >> 6, j8 = (tid & 63) * 8;
            const unsigned char* zr = zw + bb * HIDN + j8;
            const unsigned int t2b = tag2 * 0x01010101u;
            unsigned int vx, vy;
            for (;;) {
                vx = __hip_atomic_load((const unsigned int*)zr,
                                       __ATOMIC_RELAXED, __HIP_MEMORY_SCOPE_AGENT);
                vy = __hip_atomic_load((const unsigned int*)(zr + 4),
                                       __ATOMIC_RELAXED, __HIP_MEMORY_SCOPE_AGENT);
                if (((vx & 0xFEFEFEFEu) == t2b) && ((vy & 0xFEFEFEFEu) == t2b))
                    break;
                __builtin_amdgcn_s_sleep(1);
            }
            float4 o0, o1;
            o0.x = (float)(vx & 1u);         o0.y = (float)((vx >> 8) & 1u);
            o0.z = (float)((vx >> 16) & 1u); o0.w = (float)((vx >> 24) & 1u);
            o1.x = (float)(vy & 1u);         o1.y = (float)((vy >> 8) & 1u);
            o1.z = (float)((vy >> 16) & 1u); o1.w = (float)((vy >> 24) & 1u);
            *(float4*)&zfb[bb * 512 + j8] = o0;
            *(float4*)&zfb[bb * 512 + j8 + 4] = o1;
        }
        __syncthreads();   // B4: zf ready for LI + next gather

        // ---- LI readout for step t (frozen chain; wave = batch wv) ----
#pragma unroll
        for (int oo = 0; oo < 2; ++oo) {
            int o = (oo == 0) ? c : (c < 2 ? 8 + c : -1);
            if (o < 0) continue;
            double part = 0.0;
#pragma unroll
            for (int c2 = 0; c2 < 8; ++c2) {
                double zfv = (double)zfb[wv * 512 + (c2 << 6) + lane];
                part = __fma_rn(zfv, (double)wout2[oo][(c2 << 6) + lane], part);
            }
#pragma unroll
            for (int off = 32; off > 0; off >>= 1) part += __shfl_down(part, off);
            if (lane == 0) {
                float inp = (float)part;
                float vvv = (oo == 0) ? vA : vB;
                float iiv = (oo == 0) ? iA : iB;
                float vn = __fadd_rn(vvv, __fmul_rn(1e-8f, __fsub_rn(iiv, vvv)));
                float t2 = __fmul_rn(2e-8f, iiv);
                float in2 = __fadd_rn(__fsub_rn(iiv, t2), inp);
                if (oo == 0) { vA = vn; iA = in2; } else { vB = vn; iB = in2; }
                out[((size_t)t * NB + (b0 + wv)) * NOUT + o] = vn;
            }
        }
    }
}

extern "C" void kernel_launch(void* const* d_in, const int* in_sizes, int n_in,
                              void* d_out, int out_size, void* d_ws, size_t ws_size,
                              hipStream_t stream) {
    (void)in_sizes; (void)n_in; (void)out_size;
    const float* x     = (const float*)d_in[0];
    const float* w_in  = (const float*)d_in[1];
    const float* w_rec = (const float*)d_in[2];
    const float* w_out = (const float*)d_in[3];
    float* out = (float*)d_out;
    float* ws  = (float*)d_ws;
    if (ws_size < (size_t)WS_FLOATS * 4) return;

    float* wT = ws + OFF_WT;
    unsigned char* zb = (unsigned char*)(ws + OFF_ZB);
    unsigned int* ctr = (unsigned int*)(ws + OFF_CTR);
    unsigned int* mode = ctr + 1023;
    float* ci = ws + OFF_CI;

    hipLaunchKernelGGL(init_kernel, dim3((OFF_CI + 255) / 256), dim3(256), 0,
                       stream, ws, w_rec);
    hipLaunchKernelGGL(probe_kernel, dim3(1), dim3(64), 0, stream, mode);
    hipLaunchKernelGGL(gemm_mfma3, dim3(4, 400), dim3(256), 0, stream,
                       x, w_in, ci, mode);
    hipLaunchKernelGGL(gemm_vec, dim3(4, 200), dim3(256), 0, stream,
                       x, w_in, ci, mode);
    hipLaunchKernelGGL(fused_tag, dim3(NB), dim3(512), 0, stream,
                       ci, wT, w_out, out, zb);
}

// Round 20
// 1569.618 us; speedup vs baseline: 1.5298x; 1.0039x over previous
//
#include <hip/hip_runtime.h>
#include <cstdint>
#include <cstddef>

#define TSTEPS 100
#define NB 256
#define INF 2312
#define HIDN 512
#define NOUT 10
#define NTILES 1600               // (25600/64) x (512/128)

// ws layout (float offsets) — as R19; ctr[0]=tile queue, ctr[1023]=mode
#define OFF_WT  0                 // 262144 floats (w_rec transposed, 1 MB)
#define OFF_ZB  262144            // 65536 floats = [2][256][512] u8 z-transit
#define OFF_CTR 327680            // 1024 u32; [0]=queue, [1023]=mode
#define OFF_CI  328704            // 13107200 floats (input-projection cache)
#define WS_FLOATS 13435904        // 53.7 MB

typedef double f64x4 __attribute__((ext_vector_type(4)));

// D-layout candidates for mfma_f64_16x16x4: lane l, reg r -> (row m, col n)
__device__ __forceinline__ void dpos_f64(int di, int lane, int r, int& m, int& n) {
    const int l16 = lane & 15, kq = lane >> 4;
    switch (di) {
    case 0:  m = 4 * kq + r;         n = l16;                break;
    case 1:  m = l16;                n = 4 * kq + r;         break;
    case 2:  m = kq + 4 * r;         n = l16;                break;
    case 3:  m = l16;                n = kq + 4 * r;         break;
    case 4:  m = lane >> 2;          n = 4 * (lane & 3) + r; break;
    default: n = lane >> 2;          m = 4 * (lane & 3) + r; break;
    }
}

// build w_recT[j][h] = w_rec[h][j]; zero z-transit + counters (incl. queue) + mode
__global__ __launch_bounds__(256) void init_kernel(float* __restrict__ ws,
                                                   const float* __restrict__ w_rec) {
    int n = blockIdx.x * 256 + threadIdx.x;
    if (n < HIDN * HIDN) {
        int j = n >> 9, h = n & 511;
        ws[n] = w_rec[h * HIDN + j];
    } else if (n < OFF_CI) {
        ws[n] = 0.0f;
    }
}

// Exact-integer layout decoder (VERBATIM R14; HW-verified R14/R16/R19).
__global__ __launch_bounds__(64) void probe_kernel(unsigned int* __restrict__ mode_out) {
    const int l = threadIdx.x;
    __shared__ unsigned int maskls;
    if (l == 0) maskls = 0xFFFFFFu;
    __syncthreads();
    double a1v = 1.0 + 3.0 * (double)l, b1v = 2.0 + 5.0 * (double)l;
    double a2v = 7.0 - 2.0 * (double)l, b2v = -3.0 + (double)l;
    f64x4 pacc;
#pragma unroll
    for (int r = 0; r < 4; ++r) pacc[r] = 1000.0 * r + 17.0 * l;
    pacc = __builtin_amdgcn_mfma_f64_16x16x4f64(a1v, b1v, pacc, 0, 0, 0);
    pacc = __builtin_amdgcn_mfma_f64_16x16x4f64(a2v, b2v, pacc, 0, 0, 0);
    unsigned int my = 0;
    for (int ai = 0; ai < 2; ++ai)
        for (int bi = 0; bi < 2; ++bi)
            for (int di = 0; di < 6; ++di) {
                bool ok = true;
                for (int r = 0; r < 4; ++r) {
                    int m, n; dpos_f64(di, l, r, m, n);
                    double e = 1000.0 * r + 17.0 * l;
                    for (int k = 0; k < 4; ++k) {
                        int lA = ai ? (4 * m + k) : (m + 16 * k);
                        int lB = bi ? (4 * n + k) : (n + 16 * k);
                        e += (1.0 + 3.0 * (double)lA) * (2.0 + 5.0 * (double)lB)
                           + (7.0 - 2.0 * (double)lA) * (-3.0 + (double)lB);
                    }
                    ok = ok && (pacc[r] == e);
                }
                if (ok) my |= 1u << (ai * 12 + bi * 6 + di);
            }
    atomicAnd(&maskls, my);
    __syncthreads();
    if (l == 0) mode_out[0] = maskls ? (unsigned)(__ffs((int)maskls) - 1) : 255u;
}

// MFMA f64 GEMM v4: PERSISTENT WORK-QUEUE. Grid = 768 blocks (exactly 3/CU by
// LDS+VGPR budget); each block pulls 64x128 tiles from a device-scope atomic
// queue (zeroed by init each launch -> replay-safe; no inter-block waits ->
// deadlock-free at any residency). Tile body VERBATIM R16 gemm_mfma3 -> the
// per-element MFMA k-sequence is unchanged -> bit-identical ci (fingerprint).
// This removes the 2.08-rounds-runs-as-3 scheduling quantization (the ~30%
// MfmaUtil gap): makespan ~ work/768 + one tile tail.
__global__ __launch_bounds__(256, 3) void gemm_mfma4(const float* __restrict__ X,
        const float* __restrict__ Win, float* __restrict__ C,
        const unsigned int* __restrict__ modep, unsigned int* __restrict__ q) {
    const unsigned int mode = modep[0];
    if (mode >= 24u) return;
    const int di = (int)(mode % 6u), bi = (int)((mode / 6u) & 1u), ai = (int)(mode / 12u);
    __shared__ float As[32][72];     // [k][row], 9 KB, stride 72 (==8 mod 32 banks)
    __shared__ float Bs[32][144];    // [k][col], 18 KB, stride 144 (==16 mod 32)
    __shared__ unsigned int tilej;
    const int tid = threadIdx.x;
    const int lane = tid & 63, wv = tid >> 6;
    const int a_m = ai ? (lane >> 2) : (lane & 15);
    const int a_k = ai ? (lane & 3) : (lane >> 4);
    const int b_n = bi ? (lane >> 2) : (lane & 15);
    const int b_k = bi ? (lane & 3) : (lane >> 4);
    const int sra = tid >> 2, ska = (tid & 3) * 8;    // A staging: 8 floats
    const int srb = tid >> 1, skb = (tid & 1) * 16;   // B staging: 16 floats

    for (;;) {
        if (tid == 0) tilej = atomicAdd(q, 1u);
        __syncthreads();                 // broadcast tilej; also fences LDS reuse
        const unsigned int j = tilej;
        if (j >= NTILES) break;
        const int row0 = (int)(j >> 2) * 64, col0 = (int)(j & 3) * 128;

        float4 va[2], vb[4];
#pragma unroll
        for (int qq = 0; qq < 2; ++qq)
            va[qq] = *(const float4*)(X + (size_t)(row0 + sra) * INF + ska + qq * 4);
#pragma unroll
        for (int qq = 0; qq < 4; ++qq)
            vb[qq] = *(const float4*)(Win + (size_t)(col0 + srb) * INF + skb + qq * 4);

        f64x4 acc[8] = {};
        for (int k0 = 0; k0 < INF; k0 += 32) {
            __syncthreads();
#pragma unroll
            for (int qq = 0; qq < 2; ++qq) {
                int kc = ska + qq * 4;
                As[kc + 0][sra] = va[qq].x; As[kc + 1][sra] = va[qq].y;
                As[kc + 2][sra] = va[qq].z; As[kc + 3][sra] = va[qq].w;
            }
#pragma unroll
            for (int qq = 0; qq < 4; ++qq) {
                int kc = skb + qq * 4;
                Bs[kc + 0][srb] = vb[qq].x; Bs[kc + 1][srb] = vb[qq].y;
                Bs[kc + 2][srb] = vb[qq].z; Bs[kc + 3][srb] = vb[qq].w;
            }
            __syncthreads();
            const int kn = k0 + 32;
            if (kn < INF) {
#pragma unroll
                for (int qq = 0; qq < 2; ++qq) {
                    int gk = kn + ska + qq * 4;
                    float4 a = make_float4(0.f, 0.f, 0.f, 0.f);
                    if (gk < INF)   // INF%4==0 -> full float4 in-bounds
                        a = *(const float4*)(X + (size_t)(row0 + sra) * INF + gk);
                    va[qq] = a;
                }
#pragma unroll
                for (int qq = 0; qq < 4; ++qq) {
                    int gk = kn + skb + qq * 4;
                    float4 b = make_float4(0.f, 0.f, 0.f, 0.f);
                    if (gk < INF)
                        b = *(const float4*)(Win + (size_t)(col0 + srb) * INF + gk);
                    vb[qq] = b;
                }
            }
#pragma unroll
            for (int s = 0; s < 8; ++s) {
                double a = (double)As[s * 4 + a_k][wv * 16 + a_m];
#pragma unroll
                for (int nt = 0; nt < 8; ++nt) {
                    double b = (double)Bs[s * 4 + b_k][nt * 16 + b_n];
                    acc[nt] = __builtin_amdgcn_mfma_f64_16x16x4f64(a, b, acc[nt], 0, 0, 0);
                }
            }
        }
#pragma unroll
        for (int nt = 0; nt < 8; ++nt)
#pragma unroll
            for (int r = 0; r < 4; ++r) {
                int m, n; dpos_f64(di, lane, r, m, n);
                C[(size_t)(row0 + wv * 16 + m) * HIDN + col0 + nt * 16 + n]
                    = (float)acc[nt][r];
            }
    }
}

// Vector GEMM fallback: VERBATIM R10 (frozen chain). Runs only if mode==255.
__global__ __launch_bounds__(256, 2) void gemm_vec(const float* __restrict__ X,
        const float* __restrict__ Win, float* __restrict__ C,
        const unsigned int* __restrict__ modep) {
    if (modep[0] < 24u) return;
    __shared__ double As[32][130];
    __shared__ double Bs[32][144];
    const int tid = threadIdx.x;
    const int tx = tid & 15;
    const int ty = tid >> 4;
    const int row0 = blockIdx.y * 128, col0 = blockIdx.x * 128;
    const int sr = tid >> 1, sk = (tid & 1) * 16;
    const int srz = sr + (sr >> 3);
    float4 va[4], vb[4];
#pragma unroll
    for (int q = 0; q < 4; ++q) {
        int gk = sk + q * 4;
        va[q] = *(const float4*)(X + (size_t)(row0 + sr) * INF + gk);
        vb[q] = *(const float4*)(Win + (size_t)(col0 + sr) * INF + gk);
    }
    double acc[8][8] = {};
    for (int k0 = 0; k0 < INF; k0 += 32) {
        __syncthreads();
#pragma unroll
        for (int q = 0; q < 4; ++q) {
            int kc = sk + q * 4;
            As[kc + 0][sr] = (double)va[q].x; As[kc + 1][sr] = (double)va[q].y;
            As[kc + 2][sr] = (double)va[q].z; As[kc + 3][sr] = (double)va[q].w;
            Bs[kc + 0][srz] = (double)vb[q].x; Bs[kc + 1][srz] = (double)vb[q].y;
            Bs[kc + 2][srz] = (double)vb[q].z; Bs[kc + 3][srz] = (double)vb[q].w;
        }
        __syncthreads();
        const int kn = k0 + 32;
        if (kn < INF) {
#pragma unroll
            for (int q = 0; q < 4; ++q) {
                int gk = kn + sk + q * 4;
                float4 a = make_float4(0.f, 0.f, 0.f, 0.f);
                float4 b = make_float4(0.f, 0.f, 0.f, 0.f);
                if (gk < INF) {
                    a = *(const float4*)(X + (size_t)(row0 + sr) * INF + gk);
                    b = *(const float4*)(Win + (size_t)(col0 + sr) * INF + gk);
                }
                va[q] = a; vb[q] = b;
            }
        }
#pragma unroll 4
        for (int kk = 0; kk < 32; ++kk) {
            double ad[8], bd[8];
#pragma unroll
            for (int i = 0; i < 8; ++i) ad[i] = As[kk][ty * 8 + i];
#pragma unroll
            for (int j = 0; j < 8; ++j) bd[j] = Bs[kk][9 * tx + j];
#pragma unroll
            for (int i = 0; i < 8; ++i)
#pragma unroll
                for (int j = 0; j < 8; ++j)
                    acc[i][j] += ad[i] * bd[j];
        }
    }
#pragma unroll
    for (int i = 0; i < 8; ++i) {
#pragma unroll
        for (int jj = 0; jj < 2; ++jj) {
            float4 o;
            o.x = (float)acc[i][jj * 4 + 0]; o.y = (float)acc[i][jj * 4 + 1];
            o.z = (float)acc[i][jj * 4 + 2]; o.w = (float)acc[i][jj * 4 + 3];
            *(float4*)(C + (size_t)(row0 + ty * 8 + i) * HIDN + col0 + tx * 8 + jj * 4) = o;
        }
    }
}

// Fused stepper with TAG-EMBEDDED z exchange. VERBATIM R19 (~250us, verified).
__global__ __launch_bounds__(512) void fused_tag(const float* __restrict__ ci,
        const float* __restrict__ wT, const float* __restrict__ w_out,
        float* __restrict__ out, unsigned char* __restrict__ zb) {
    __shared__ float zfb[4096];        // 16 KB union: zf[b][j] | fbufT[c2][b][h]
    __shared__ float wout2[2][512];    // 4 KB
    const int tid = threadIdx.x;
    const int wv = tid >> 6, lane = tid & 63;
    const int i = (int)blockIdx.x;
    const int c = (i >> 3) & 7;                    // h-chunk / group member
    const int g = (i & 7) | ((i >> 6) << 3);       // group 0..31 (co-XCD)
    const int b0 = g * 8;

    float wreg[64];
#pragma unroll
    for (int qq = 0; qq < 64; ++qq)
        wreg[qq] = wT[(size_t)((wv << 6) + qq) * HIDN + (c << 6) + lane];

    if (tid < 512) {
        wout2[0][tid] = w_out[c * HIDN + tid];
        wout2[1][tid] = (c < 2) ? w_out[(8 + c) * HIDN + tid] : 0.0f;
    }
    for (int idx = tid; idx < 4096; idx += 512) zfb[idx] = 0.0f;  // z_{-1}=0
    __syncthreads();

    unsigned char* zbA = zb + (size_t)b0 * HIDN;            // [b][j] u8
    unsigned char* zbB = zb + 131072 + (size_t)b0 * HIDN;

    float pos = 0.0f;                  // fold phase: thread = (batch wv, h lane)
    float vA = 0.f, iA = 0.f, vB = 0.f, iB = 0.f;   // LI state on lane 0

    for (int t = 0; t < TSTEPS; ++t) {
        // ---- gather (frozen fmac chains, verbatim R9) ----
        float f[8] = {0.f, 0.f, 0.f, 0.f, 0.f, 0.f, 0.f, 0.f};
#pragma unroll
        for (int q4 = 0; q4 < 16; ++q4) {
            float4 z4[8];
#pragma unroll
            for (int b = 0; b < 8; ++b)
                z4[b] = *(const float4*)&zfb[b * 512 + (wv << 6) + q4 * 4];
#pragma unroll
            for (int b = 0; b < 8; ++b) {
                f[b] = __fmaf_rn(z4[b].x, wreg[q4 * 4 + 0], f[b]);
                f[b] = __fmaf_rn(z4[b].y, wreg[q4 * 4 + 1], f[b]);
                f[b] = __fmaf_rn(z4[b].z, wreg[q4 * 4 + 2], f[b]);
                f[b] = __fmaf_rn(z4[b].w, wreg[q4 * 4 + 3], f[b]);
            }
        }
        __syncthreads();   // B1: all zf reads done; region becomes fbufT
#pragma unroll
        for (int b = 0; b < 8; ++b)
            zfb[((wv << 3) + b) * 64 + lane] = f[b];   // fbufT[c2=wv][b][h]
        __syncthreads();   // B2: partials published

        // ---- fold + neuron update (frozen) + tagged z publish ----
        double acc = 0.0;
#pragma unroll
        for (int c2 = 0; c2 < 8; ++c2)
            acc += (double)zfb[((c2 << 3) + wv) * 64 + lane];
        float rec32 = (float)acc;
        float civ = ci[((size_t)t * NB + (b0 + wv)) * HIDN + (c << 6) + lane];
        float cur = __fadd_rn(__fadd_rn(civ, rec32), 1e-4f);   // (in+rec)+I_APP
        float mc = __fmul_rn(2.5e5f, cur);                     // MU*cur
        pos = __fadd_rn(pos, __fmul_rn(1e-10f, mc));           // pos += DT*(..)
        bool zbit = __fsub_rn(pos, 2.5e-8f) > 0.0f;            // pos-W2 > 0
        pos = zbit ? 0.0f : pos;
        unsigned char* zw = (t & 1) ? zbB : zbA;
        const unsigned int tag2 = ((unsigned)(t >> 1) + 1u) << 1;   // <=101
        __hip_atomic_store(&zw[wv * HIDN + (c << 6) + lane],
                           (unsigned char)(tag2 | (zbit ? 1u : 0u)),
                           __ATOMIC_RELAXED, __HIP_MEMORY_SCOPE_AGENT);
        __syncthreads();   // B3: fbufT reads done -> zfb reusable as zf

        // ---- pull z_t: poll tagged bytes (data == flag) ----
        {
            const int bb = tid >> 6, j8 = (tid & 63) * 8;
            const unsigned char* zr = zw + bb * HIDN + j8;
            const unsigned int t2b = tag2 * 0x01010101u;
            unsigned int vx, vy;
            for (;;) {
                vx = __hip_atomic_load((const unsigned int*)zr,
                                       __ATOMIC_RELAXED, __HIP_MEMORY_SCOPE_AGENT);
                vy = __hip_atomic_load((const unsigned int*)(zr + 4),
                                       __ATOMIC_RELAXED, __HIP_MEMORY_SCOPE_AGENT);
                if (((vx & 0xFEFEFEFEu) == t2b) && ((vy & 0xFEFEFEFEu) == t2b))
                    break;
                __builtin_amdgcn_s_sleep(1);
            }
            float4 o0, o1;
            o0.x = (float)(vx & 1u);         o0.y = (float)((vx >> 8) & 1u);
            o0.z = (float)((vx >> 16) & 1u); o0.w = (float)((vx >> 24) & 1u);
            o1.x = (float)(vy & 1u);         o1.y = (float)((vy >> 8) & 1u);
            o1.z = (float)((vy >> 16) & 1u); o1.w = (float)((vy >> 24) & 1u);
            *(float4*)&zfb[bb * 512 + j8] = o0;
            *(float4*)&zfb[bb * 512 + j8 + 4] = o1;
        }
        __syncthreads();   // B4: zf ready for LI + next gather

        // ---- LI readout for step t (frozen chain; wave = batch wv) ----
#pragma unroll
        for (int oo = 0; oo < 2; ++oo) {
            int o = (oo == 0) ? c : (c < 2 ? 8 + c : -1);
            if (o < 0) continue;
            double part = 0.0;
#pragma unroll
            for (int c2 = 0; c2 < 8; ++c2) {
                double zfv = (double)zfb[wv * 512 + (c2 << 6) + lane];
                part = __fma_rn(zfv, (double)wout2[oo][(c2 << 6) + lane], part);
            }
#pragma unroll
            for (int off = 32; off > 0; off >>= 1) part += __shfl_down(part, off);
            if (lane == 0) {
                float inp = (float)part;
                float vvv = (oo == 0) ? vA : vB;
                float iiv = (oo == 0) ? iA : iB;
                float vn = __fadd_rn(vvv, __fmul_rn(1e-8f, __fsub_rn(iiv, vvv)));
                float t2 = __fmul_rn(2e-8f, iiv);
                float in2 = __fadd_rn(__fsub_rn(iiv, t2), inp);
                if (oo == 0) { vA = vn; iA = in2; } else { vB = vn; iB = in2; }
                out[((size_t)t * NB + (b0 + wv)) * NOUT + o] = vn;
            }
        }
    }
}

extern "C" void kernel_launch(void* const* d_in, const int* in_sizes, int n_in,
                              void* d_out, int out_size, void* d_ws, size_t ws_size,
                              hipStream_t stream) {
    (void)in_sizes; (void)n_in; (void)out_size;
    const float* x     = (const float*)d_in[0];
    const float* w_in  = (const float*)d_in[1];
    const float* w_rec = (const float*)d_in[2];
    const float* w_out = (const float*)d_in[3];
    float* out = (float*)d_out;
    float* ws  = (float*)d_ws;
    if (ws_size < (size_t)WS_FLOATS * 4) return;

    float* wT = ws + OFF_WT;
    unsigned char* zb = (unsigned char*)(ws + OFF_ZB);
    unsigned int* ctr = (unsigned int*)(ws + OFF_CTR);
    unsigned int* queue = ctr;         // [0], zeroed by init each launch
    unsigned int* mode = ctr + 1023;
    float* ci = ws + OFF_CI;

    hipLaunchKernelGGL(init_kernel, dim3((OFF_CI + 255) / 256), dim3(256), 0,
                       stream, ws, w_rec);
    hipLaunchKernelGGL(probe_kernel, dim3(1), dim3(64), 0, stream, mode);
    hipLaunchKernelGGL(gemm_mfma4, dim3(768), dim3(256), 0, stream,
                       x, w_in, ci, mode, queue);
    hipLaunchKernelGGL(gemm_vec, dim3(4, 200), dim3(256), 0, stream,
                       x, w_in, ci, mode);
    hipLaunchKernelGGL(fused_tag, dim3(NB), dim3(512), 0, stream,
                       ci, wT, w_out, out, zb);
}